// Round 2
// baseline (49569.324 us; speedup 1.0000x reference)
//
#include <hip/hip_runtime.h>
#include <cstdint>
#include <cstddef>

#define DEVFN __device__ __forceinline__

DEVFN float sigmf(float x) { return 1.0f / (1.0f + expf(-x)); }

// =====================================================================
// GEMM v2: C[rowmap(m), n] = act( sum_k A[m,k]*B[n,k] + bias[n] )
// A: (M,K) row-major. B: (N,K) row-major (weights, i.e. C = A @ B^T).
// Block 256 thr = 4 waves (2x2), macro-tile 128x128, BK=16.
// Both operands staged TRANSPOSED in LDS as [k][m]/[k][n], stride 132
// (conflict-free transpose writes AND float4-aligned broadcast reads).
// Per-lane 8x8 register tile; double-buffered LDS, 1 barrier per K-step.
// RMAP: 0 identity; 1: (m%80)*128+m/80 ; 2: (m&127)*10+(m>>7)
// Requires: M%128==0, N%128==0, K%16==0.
// =====================================================================
template <int ACT, int RMAP>
__global__ __launch_bounds__(256, 4) void gemm_k(
    const float* __restrict__ A, const float* __restrict__ B,
    const float* __restrict__ bias, float* __restrict__ C, int K, int ldc) {
  constexpr int SST = 132;
  __shared__ float As[2][16 * SST];
  __shared__ float Bs[2][16 * SST];
  const int tid = threadIdx.x;
  const int mA = blockIdx.y * 128;
  const int n0 = blockIdx.x * 128;

  // staging assignment: 64 rows x 4 k-quads per pass, 2 passes (rows +64)
  const int sm = tid >> 2;  // 0..63
  const int sq = tid & 3;   // 0..3 k-quad
  const float* __restrict__ Ap0 = A + (size_t)(mA + sm) * K + sq * 4;
  const float* __restrict__ Ap1 = A + (size_t)(mA + sm + 64) * K + sq * 4;
  const float* __restrict__ Bp0 = B + (size_t)(n0 + sm) * K + sq * 4;
  const float* __restrict__ Bp1 = B + (size_t)(n0 + sm + 64) * K + sq * 4;

  const int w = tid >> 6;
  const int lane = tid & 63;
  const int ma0 = (w >> 1) * 64 + (lane >> 3) * 4;  // LDS m base
  const int nb0 = (w & 1) * 64 + (lane & 7) * 4;    // LDS n base

  float acc[8][8];
#pragma unroll
  for (int i = 0; i < 8; ++i)
#pragma unroll
    for (int j = 0; j < 8; ++j) acc[i][j] = 0.f;

#define STAGE_WR(AW, BW, a0_, a1_, b0_, b1_)                   \
  do {                                                         \
    const int kq = sq * 4;                                     \
    (AW)[(kq + 0) * SST + sm] = (a0_).x;                       \
    (AW)[(kq + 1) * SST + sm] = (a0_).y;                       \
    (AW)[(kq + 2) * SST + sm] = (a0_).z;                       \
    (AW)[(kq + 3) * SST + sm] = (a0_).w;                       \
    (AW)[(kq + 0) * SST + sm + 64] = (a1_).x;                  \
    (AW)[(kq + 1) * SST + sm + 64] = (a1_).y;                  \
    (AW)[(kq + 2) * SST + sm + 64] = (a1_).z;                  \
    (AW)[(kq + 3) * SST + sm + 64] = (a1_).w;                  \
    (BW)[(kq + 0) * SST + sm] = (b0_).x;                       \
    (BW)[(kq + 1) * SST + sm] = (b0_).y;                       \
    (BW)[(kq + 2) * SST + sm] = (b0_).z;                       \
    (BW)[(kq + 3) * SST + sm] = (b0_).w;                       \
    (BW)[(kq + 0) * SST + sm + 64] = (b1_).x;                  \
    (BW)[(kq + 1) * SST + sm + 64] = (b1_).y;                  \
    (BW)[(kq + 2) * SST + sm + 64] = (b1_).z;                  \
    (BW)[(kq + 3) * SST + sm + 64] = (b1_).w;                  \
  } while (0)

  // prologue: stage tile 0 into buffer 0
  {
    const float4 a0 = *(const float4*)Ap0;
    const float4 a1 = *(const float4*)Ap1;
    const float4 b0 = *(const float4*)Bp0;
    const float4 b1 = *(const float4*)Bp1;
    STAGE_WR(As[0], Bs[0], a0, a1, b0, b1);
  }
  __syncthreads();

  const int nt = K >> 4;
  for (int t = 0; t < nt; ++t) {
    const int cur = t & 1;
    float4 gA0, gA1, gB0, gB1;
    const bool more = (t + 1) < nt;
    if (more) {
      const int kc = (t + 1) << 4;
      gA0 = *(const float4*)(Ap0 + kc);
      gA1 = *(const float4*)(Ap1 + kc);
      gB0 = *(const float4*)(Bp0 + kc);
      gB1 = *(const float4*)(Bp1 + kc);
    }
    const float* __restrict__ Ab = As[cur];
    const float* __restrict__ Bb = Bs[cur];
#pragma unroll
    for (int k = 0; k < 16; ++k) {
      const float4 a0 = *(const float4*)&Ab[k * SST + ma0];
      const float4 a1 = *(const float4*)&Ab[k * SST + ma0 + 32];
      const float4 b0 = *(const float4*)&Bb[k * SST + nb0];
      const float4 b1 = *(const float4*)&Bb[k * SST + nb0 + 32];
      const float av[8] = {a0.x, a0.y, a0.z, a0.w, a1.x, a1.y, a1.z, a1.w};
      const float bv[8] = {b0.x, b0.y, b0.z, b0.w, b1.x, b1.y, b1.z, b1.w};
#pragma unroll
      for (int i = 0; i < 8; ++i)
#pragma unroll
        for (int j = 0; j < 8; ++j) acc[i][j] += av[i] * bv[j];
    }
    if (more) STAGE_WR(As[cur ^ 1], Bs[cur ^ 1], gA0, gA1, gB0, gB1);
    __syncthreads();
  }
#undef STAGE_WR

  // epilogue: bias + activation + remapped store
  const float4 bb0 = *(const float4*)&bias[n0 + nb0];
  const float4 bb1 = *(const float4*)&bias[n0 + nb0 + 32];
  const float bv[8] = {bb0.x, bb0.y, bb0.z, bb0.w, bb1.x, bb1.y, bb1.z, bb1.w};
#pragma unroll
  for (int i = 0; i < 8; ++i) {
    const int m = mA + ma0 + (i < 4 ? i : 28 + i);
    int cr;
    if (RMAP == 0) cr = m;
    else if (RMAP == 1) cr = (m % 80) * 128 + m / 80;
    else cr = (m & 127) * 10 + (m >> 7);
    float* Cp = C + (size_t)cr * ldc + n0 + nb0;
    float4 o0, o1;
    float v;
    v = acc[i][0] + bv[0]; o0.x = ACT ? fmaxf(v, 0.f) : v;
    v = acc[i][1] + bv[1]; o0.y = ACT ? fmaxf(v, 0.f) : v;
    v = acc[i][2] + bv[2]; o0.z = ACT ? fmaxf(v, 0.f) : v;
    v = acc[i][3] + bv[3]; o0.w = ACT ? fmaxf(v, 0.f) : v;
    v = acc[i][4] + bv[4]; o1.x = ACT ? fmaxf(v, 0.f) : v;
    v = acc[i][5] + bv[5]; o1.y = ACT ? fmaxf(v, 0.f) : v;
    v = acc[i][6] + bv[6]; o1.z = ACT ? fmaxf(v, 0.f) : v;
    v = acc[i][7] + bv[7]; o1.w = ACT ? fmaxf(v, 0.f) : v;
    *(float4*)&Cp[0] = o0;
    *(float4*)&Cp[32] = o1;
  }
}

// =====================================================================
// One GRU recurrence step. Grid: (jt=64, bt=4, d=dirs). Block 256.
// gh = h_prev @ whh^T (+bhh), gates fused, writes h_next and y.
// gi rows are (t*128+b), columns [d*1536 + gate*512 + j].
// h buffers: (dirs,128,512). y row (t*128+b), y_ld cols, offset d*512.
// =====================================================================
__global__ __launch_bounds__(256, 2) void gru_step_k(
    const float* __restrict__ h_prev, float* __restrict__ h_next,
    const float* __restrict__ gi, int gi_ld, const float* __restrict__ whh,
    const float* __restrict__ bhh, float* __restrict__ y, int y_ld, int i,
    int T) {
  __shared__ float lds_h[32 * 516];
  __shared__ float gh_lds[24 * 33];
  const int tid = threadIdx.x;
  const int jt = blockIdx.x; // 0..63  (8 h-outputs each)
  const int bt = blockIdx.y; // 0..3   (32 batch rows each)
  const int d = blockIdx.z;
  const int t_d = (d == 0) ? i : (T - 1 - i);
  const int doff = d * 1536;

  // stage h tile (32 x 512) into LDS, stride 516
  {
    const float* hp = h_prev + ((size_t)(d * 128 + bt * 32)) * 512;
#pragma unroll
    for (int c = 0; c < 16; ++c) {
      const int i4 = c * 256 + tid;
      const int r = i4 >> 7;
      const int k4 = i4 & 127;
      *(float4*)&lds_h[r * 516 + k4 * 4] =
          *(const float4*)&hp[(size_t)r * 512 + k4 * 4];
    }
  }
  __syncthreads();

  const int w = __builtin_amdgcn_readfirstlane(tid >> 6);
  const int lane = tid & 63;
  const int b_loc = lane & 31;
  const int kh = lane >> 5;

  const float* wr[6];
#pragma unroll
  for (int q = 0; q < 6; ++q) {
    const int rl = w * 6 + q;
    const int g = rl >> 3, jh = rl & 7;
    wr[q] = whh + ((size_t)(doff + g * 512 + jt * 8 + jh)) * 512;
  }
  float acc[6] = {0.f, 0.f, 0.f, 0.f, 0.f, 0.f};
  const int kbase = kh * 256;
  for (int k8 = 0; k8 < 256; k8 += 8) {
    const float4 a0 = *(const float4*)&lds_h[b_loc * 516 + kbase + k8];
    const float4 a1 = *(const float4*)&lds_h[b_loc * 516 + kbase + k8 + 4];
#pragma unroll
    for (int q = 0; q < 6; ++q) {
      const float* r_ = wr[q] + kbase + k8;
      acc[q] += r_[0] * a0.x + r_[1] * a0.y + r_[2] * a0.z + r_[3] * a0.w +
                r_[4] * a1.x + r_[5] * a1.y + r_[6] * a1.z + r_[7] * a1.w;
    }
  }
#pragma unroll
  for (int q = 0; q < 6; ++q) acc[q] += __shfl_xor(acc[q], 32);
  if (kh == 0) {
#pragma unroll
    for (int q = 0; q < 6; ++q) gh_lds[(w * 6 + q) * 33 + b_loc] = acc[q];
  }
  __syncthreads();

  // gate phase: thread -> (jh2, b2)
  const int jh2 = tid & 7;
  const int b2 = tid >> 3; // 0..31
  const int jg = jt * 8 + jh2;
  const int bg = bt * 32 + b2;
  const float ghr = gh_lds[(jh2) * 33 + b2];
  const float ghz = gh_lds[(8 + jh2) * 33 + b2];
  const float ghn = gh_lds[(16 + jh2) * 33 + b2];
  const float* gir = gi + (size_t)(t_d * 128 + bg) * gi_ld + doff;
  const float g_r = gir[jg];
  const float g_z = gir[512 + jg];
  const float g_n = gir[1024 + jg];
  const float r = sigmf(g_r + ghr + bhh[doff + jg]);
  const float z = sigmf(g_z + ghz + bhh[doff + 512 + jg]);
  const float n = tanhf(g_n + r * (ghn + bhh[doff + 1024 + jg]));
  const float hold = lds_h[b2 * 516 + jg];
  const float hnew = (1.f - z) * n + z * hold;
  h_next[((size_t)(d * 128 + bg)) * 512 + jg] = hnew;
  y[((size_t)(t_d * 128 + bg)) * y_ld + d * 512 + jg] = hnew;
}

// =====================================================================
// encode_out[t,b,h] = y1[t,b,h] + y1[t,b,512+h]   (float4 granularity)
// =====================================================================
__global__ void fold_k(const float* __restrict__ y1, float* __restrict__ eo) {
  const size_t i = (size_t)blockIdx.x * 256 + threadIdx.x; // float4 index
  const size_t r = i >> 7;
  const int k4 = (int)(i & 127);
  const float* s = y1 + r * 1024 + k4 * 4;
  const float4 a = *(const float4*)s;
  const float4 c = *(const float4*)(s + 512);
  float4 o;
  o.x = a.x + c.x; o.y = a.y + c.y; o.z = a.z + c.z; o.w = a.w + c.w;
  *(float4*)&eo[r * 512 + k4 * 4] = o;
}

// emb_g[l*128+b, :] = embed[target[b,l], :]
__global__ void gather_k(const float* __restrict__ embed,
                         const int* __restrict__ target,
                         float* __restrict__ out) {
  const int rowid = blockIdx.x; // l*128+b
  const int l = rowid >> 7, b = rowid & 127;
  const int wd = target[b * 10 + l];
  const float4* src = (const float4*)(embed + (size_t)wd * 512);
  float4* dst = (float4*)(out + (size_t)rowid * 512);
  dst[threadIdx.x] = src[threadIdx.x];
}

// =====================================================================
// Attention per (l,b): scores over T=80, softmax, ctx; writes Z row
// [ctx(512) | hn(512)].  enc: (T,B,512) rows t*128+b. hn: (L*B,512).
// =====================================================================
__global__ __launch_bounds__(256) void attn_k(const float* __restrict__ enc,
                                              const float* __restrict__ hn_all,
                                              float* __restrict__ Z) {
  __shared__ float hs[512];
  __shared__ float sc[80];
  __shared__ float att[80];
  const int l = blockIdx.x >> 7;
  const int b = blockIdx.x & 127;
  const int tid = threadIdx.x;
  const size_t hrow = (size_t)(l * 128 + b) * 512;
  if (tid < 128)
    *(float4*)&hs[tid * 4] = *(const float4*)&hn_all[hrow + tid * 4];
  __syncthreads();
  const int w = tid >> 6, lane = tid & 63;
  for (int t = w; t < 80; t += 4) {
    const float* e = enc + ((size_t)(t * 128 + b)) * 512 + lane * 8;
    const float4 e0 = *(const float4*)e;
    const float4 e1 = *(const float4*)(e + 4);
    const float* h8 = &hs[lane * 8];
    float p = e0.x * h8[0] + e0.y * h8[1] + e0.z * h8[2] + e0.w * h8[3] +
              e1.x * h8[4] + e1.y * h8[5] + e1.z * h8[6] + e1.w * h8[7];
#pragma unroll
    for (int off = 1; off < 64; off <<= 1) p += __shfl_xor(p, off);
    if (lane == 0) sc[t] = p;
  }
  __syncthreads();
  if (w == 0) {
    const float v0 = sc[lane];
    const float v1 = (lane < 16) ? sc[64 + lane] : -3.4e38f;
    float m = fmaxf(v0, v1);
#pragma unroll
    for (int off = 1; off < 64; off <<= 1) m = fmaxf(m, __shfl_xor(m, off));
    const float e0 = expf(v0 - m);
    const float e1 = (lane < 16) ? expf(v1 - m) : 0.f;
    float s = e0 + e1;
#pragma unroll
    for (int off = 1; off < 64; off <<= 1) s += __shfl_xor(s, off);
    att[lane] = e0 / s;
    if (lane < 16) att[64 + lane] = e1 / s;
  }
  __syncthreads();
  float c0 = 0.f, c1 = 0.f;
  for (int t = 0; t < 80; ++t) {
    const float* e = enc + ((size_t)(t * 128 + b)) * 512;
    const float a = att[t];
    c0 += a * e[tid];
    c1 += a * e[tid + 256];
  }
  const size_t zr = (size_t)(l * 128 + b) * 1024;
  Z[zr + tid] = c0;
  Z[zr + 256 + tid] = c1;
  Z[zr + 512 + tid] = hs[tid];
  Z[zr + 768 + tid] = hs[256 + tid];
}

// =====================================================================
// Per row (b*10+l) of d_out: argmax (first-index ties) + logsumexp,
// in-place log_softmax, write pre_sent[l*128+b] as float.
// =====================================================================
__global__ __launch_bounds__(256) void lsm_k(float* __restrict__ out) {
  const int row = blockIdx.x; // b*10 + l
  float* p = out + (size_t)row * 32000;
  const int tid = threadIdx.x;
  float bv = -3.4e38f;
  int bi = 0;
  for (int c = 0; c < 125; ++c) {
    const int idx = c * 256 + tid;
    const float v = p[idx];
    if (v > bv || (v == bv && idx < bi)) { bv = v; bi = idx; }
  }
#pragma unroll
  for (int off = 1; off < 64; off <<= 1) {
    const float ov = __shfl_xor(bv, off);
    const int oi = __shfl_xor(bi, off);
    if (ov > bv || (ov == bv && oi < bi)) { bv = ov; bi = oi; }
  }
  __shared__ float wv[4];
  __shared__ int wi[4];
  __shared__ float wsm[4];
  const int w = tid >> 6, lane = tid & 63;
  if (lane == 0) { wv[w] = bv; wi[w] = bi; }
  __syncthreads();
  float m = wv[0];
  int mi = wi[0];
#pragma unroll
  for (int q = 1; q < 4; ++q) {
    if (wv[q] > m || (wv[q] == m && wi[q] < mi)) { m = wv[q]; mi = wi[q]; }
  }
  float s = 0.f;
  for (int c = 0; c < 125; ++c) s += expf(p[c * 256 + tid] - m);
#pragma unroll
  for (int off = 1; off < 64; off <<= 1) s += __shfl_xor(s, off);
  if (lane == 0) wsm[w] = s;
  __syncthreads();
  const float lse = m + logf(wsm[0] + wsm[1] + wsm[2] + wsm[3]);
  for (int c = 0; c < 125; ++c) {
    const int idx = c * 256 + tid;
    p[idx] = p[idx] - lse;
  }
  if (tid == 0) out[40960000 + (row % 10) * 128 + (row / 10)] = (float)mi;
}

// =====================================================================
extern "C" void kernel_launch(void* const* d_in, const int* in_sizes, int n_in,
                              void* d_out, int out_size, void* d_ws,
                              size_t ws_size, hipStream_t stream) {
  (void)in_sizes; (void)n_in; (void)out_size; (void)ws_size;
  const float* data = (const float*)d_in[0];
  const int* target = (const int*)d_in[1];
  const float* enc_lin_w = (const float*)d_in[2];
  const float* enc_lin_b = (const float*)d_in[3];
  const float* enc_wih0 = (const float*)d_in[4];
  const float* enc_whh0 = (const float*)d_in[5];
  const float* enc_bih0 = (const float*)d_in[6];
  const float* enc_bhh0 = (const float*)d_in[7];
  const float* enc_wih1 = (const float*)d_in[8];
  const float* enc_whh1 = (const float*)d_in[9];
  const float* enc_bih1 = (const float*)d_in[10];
  const float* enc_bhh1 = (const float*)d_in[11];
  const float* dec_wih = (const float*)d_in[12];
  const float* dec_whh = (const float*)d_in[13];
  const float* dec_bih = (const float*)d_in[14];
  const float* dec_bhh = (const float*)d_in[15];
  const float* out_w = (const float*)d_in[16];
  const float* out_b = (const float*)d_in[17];
  const float* embed = (const float*)d_in[18];
  float* outp = (float*)d_out;

  float* ws = (float*)d_ws;
  size_t off = 0;
  float* buf_gi = ws + off;  off += 31457280;  // (10240, 3072) gi0 then gi1
  float* buf_x = ws + off;   off += 5242880;   // x (T,B,512); later enc_out
  float* buf_y0 = ws + off;  off += 10485760;  // (T,B,1024)
  float* buf_y1 = ws + off;  off += 10485760;  // (T,B,1024)
  float* h_pp0 = ws + off;   off += 131072;    // (2,128,512)
  float* h_pp1 = ws + off;   off += 131072;
  float* dec_pp0 = ws + off; off += 65536;     // (128,512)
  float* dec_pp1 = ws + off; off += 65536;
  float* emb_g = ws + off;   off += 655360;    // (1280,512)
  float* gi_dec = ws + off;  off += 1966080;   // (1280,1536)
  float* hn_all = ws + off;  off += 655360;    // (1280,512)
  float* Zb = ws + off;      off += 1310720;   // (1280,1024)

  // ---- Encoder linear + ReLU: x(t*128+b, 512) ----
  gemm_k<1, 1><<<dim3(4, 80), 256, 0, stream>>>(data, enc_lin_w, enc_lin_b,
                                                buf_x, 4096, 512);
  // ---- gi0 = x @ wih0^T (+bih0), both dirs stacked in 3072 cols ----
  gemm_k<0, 0><<<dim3(24, 80), 256, 0, stream>>>(buf_x, enc_wih0, enc_bih0,
                                                 buf_gi, 512, 3072);
  // ---- layer-0 recurrence ----
  hipMemsetAsync(h_pp0, 0, 2 * 128 * 512 * sizeof(float), stream);
  for (int i = 0; i < 80; ++i) {
    float* hin = (i & 1) ? h_pp1 : h_pp0;
    float* hout = (i & 1) ? h_pp0 : h_pp1;
    gru_step_k<<<dim3(64, 4, 2), 256, 0, stream>>>(
        hin, hout, buf_gi, 3072, enc_whh0, enc_bhh0, buf_y0, 1024, i, 80);
  }
  // ---- gi1 = y0 @ wih1^T (+bih1) ----
  gemm_k<0, 0><<<dim3(24, 80), 256, 0, stream>>>(buf_y0, enc_wih1, enc_bih1,
                                                 buf_gi, 1024, 3072);
  // ---- layer-1 recurrence ----
  hipMemsetAsync(h_pp0, 0, 2 * 128 * 512 * sizeof(float), stream);
  for (int i = 0; i < 80; ++i) {
    float* hin = (i & 1) ? h_pp1 : h_pp0;
    float* hout = (i & 1) ? h_pp0 : h_pp1;
    gru_step_k<<<dim3(64, 4, 2), 256, 0, stream>>>(
        hin, hout, buf_gi, 3072, enc_whh1, enc_bhh1, buf_y1, 1024, i, 80);
  }
  // final hidden (both dirs) now in h_pp0; decode_hid = d=1 slice.
  // ---- encode_out = y1[:, :512] + y1[:, 512:]  (into buf_x) ----
  fold_k<<<5120, 256, 0, stream>>>(buf_y1, buf_x);
  // ---- decoder input projections ----
  gather_k<<<1280, 128, 0, stream>>>(embed, target, emb_g);
  gemm_k<0, 0><<<dim3(12, 10), 256, 0, stream>>>(emb_g, dec_wih, dec_bih,
                                                 gi_dec, 512, 1536);
  // ---- decoder hidden chain (teacher forcing => independent of logits) ----
  for (int l = 0; l < 10; ++l) {
    float* hin = (l == 0) ? (h_pp0 + 128 * 512) : ((l & 1) ? dec_pp1 : dec_pp0);
    float* hout = (l & 1) ? dec_pp0 : dec_pp1;
    gru_step_k<<<dim3(64, 4, 1), 256, 0, stream>>>(
        hin, hout, gi_dec, 1536, dec_whh, dec_bhh, hn_all, 512, l, 10);
  }
  // ---- attention + Z = [ctx | hn] ----
  attn_k<<<1280, 256, 0, stream>>>(buf_x, hn_all, Zb);
  // ---- logits GEMM straight into d_out rows (b*10+l) ----
  gemm_k<0, 2><<<dim3(250, 10), 256, 0, stream>>>(Zb, out_w, out_b, outp, 1024,
                                                  32000);
  // ---- log_softmax in place + argmax -> pre_sent ----
  lsm_k<<<1280, 256, 0, stream>>>(outp);
}

// Round 3
// 21751.833 us; speedup vs baseline: 2.2789x; 2.2789x over previous
//
#include <hip/hip_runtime.h>
#include <cstdint>
#include <cstddef>

#define DEVFN __device__ __forceinline__

DEVFN float sigmf(float x) { return 1.0f / (1.0f + expf(-x)); }

// =====================================================================
// GEMM v3: C[rowmap(m), n] = act( sum_k A[m,k]*B[n,k] + bias[n] )
// A: (M,K) row-major. B: (N,K) row-major (C = A @ B^T).
// Block 256 thr = 4 waves (2x2), macro-tile 128x128, BK=16.
// Operands staged TRANSPOSED in LDS [k][m]/[k][n], stride 132.
// Per-lane 8x8 register tile held in 16 NAMED float4s (no local arrays
// -> no scratch spill; R2's acc[8][8] + av[8]/bv[8] spilled to HBM).
// Double-buffered LDS, 1 barrier per K-step.
// RMAP: 0 identity; 1: (m%80)*128+m/80 ; 2: (m&127)*10+(m>>7)
// Requires: M%128==0, N%128==0, K%16==0.
// =====================================================================
template <int ACT, int RMAP>
__global__ __launch_bounds__(256, 2) void gemm_k(
    const float* __restrict__ A, const float* __restrict__ B,
    const float* __restrict__ bias, float* __restrict__ C, int K, int ldc) {
  constexpr int SST = 132;
  __shared__ float As[2][16 * SST];
  __shared__ float Bs[2][16 * SST];
  const int tid = threadIdx.x;
  const int mA = blockIdx.y * 128;
  const int n0 = blockIdx.x * 128;

  // staging assignment: 64 rows x 4 k-quads, 2 row-passes (+64)
  const int sm = tid >> 2;  // 0..63
  const int sq = tid & 3;   // 0..3 k-quad
  const float* __restrict__ Ap0 = A + (size_t)(mA + sm) * K + sq * 4;
  const float* __restrict__ Ap1 = A + (size_t)(mA + sm + 64) * K + sq * 4;
  const float* __restrict__ Bp0 = B + (size_t)(n0 + sm) * K + sq * 4;
  const float* __restrict__ Bp1 = B + (size_t)(n0 + sm + 64) * K + sq * 4;

  const int w = tid >> 6;
  const int lane = tid & 63;
  const int ma0 = (w >> 1) * 64 + (lane >> 3) * 4;  // LDS m base
  const int nb0 = (w & 1) * 64 + (lane & 7) * 4;    // LDS n base

  const float4 fz = {0.f, 0.f, 0.f, 0.f};
  float4 c00 = fz, c01 = fz, c10 = fz, c11 = fz, c20 = fz, c21 = fz,
         c30 = fz, c31 = fz, c40 = fz, c41 = fz, c50 = fz, c51 = fz,
         c60 = fz, c61 = fz, c70 = fz, c71 = fz;

#define STAGE_WR(AW, BW, a0_, a1_, b0_, b1_)                   \
  do {                                                         \
    const int kq = sq * 4;                                     \
    (AW)[(kq + 0) * SST + sm] = (a0_).x;                       \
    (AW)[(kq + 1) * SST + sm] = (a0_).y;                       \
    (AW)[(kq + 2) * SST + sm] = (a0_).z;                       \
    (AW)[(kq + 3) * SST + sm] = (a0_).w;                       \
    (AW)[(kq + 0) * SST + sm + 64] = (a1_).x;                  \
    (AW)[(kq + 1) * SST + sm + 64] = (a1_).y;                  \
    (AW)[(kq + 2) * SST + sm + 64] = (a1_).z;                  \
    (AW)[(kq + 3) * SST + sm + 64] = (a1_).w;                  \
    (BW)[(kq + 0) * SST + sm] = (b0_).x;                       \
    (BW)[(kq + 1) * SST + sm] = (b0_).y;                       \
    (BW)[(kq + 2) * SST + sm] = (b0_).z;                       \
    (BW)[(kq + 3) * SST + sm] = (b0_).w;                       \
    (BW)[(kq + 0) * SST + sm + 64] = (b1_).x;                  \
    (BW)[(kq + 1) * SST + sm + 64] = (b1_).y;                  \
    (BW)[(kq + 2) * SST + sm + 64] = (b1_).z;                  \
    (BW)[(kq + 3) * SST + sm + 64] = (b1_).w;                  \
  } while (0)

#define FMA_ROW(AV, C0, C1)          \
  C0.x = fmaf(AV, b0.x, C0.x);       \
  C0.y = fmaf(AV, b0.y, C0.y);       \
  C0.z = fmaf(AV, b0.z, C0.z);       \
  C0.w = fmaf(AV, b0.w, C0.w);       \
  C1.x = fmaf(AV, b1.x, C1.x);       \
  C1.y = fmaf(AV, b1.y, C1.y);       \
  C1.z = fmaf(AV, b1.z, C1.z);       \
  C1.w = fmaf(AV, b1.w, C1.w);

  // prologue: stage tile 0 into buffer 0
  {
    const float4 a0 = *(const float4*)Ap0;
    const float4 a1 = *(const float4*)Ap1;
    const float4 b0 = *(const float4*)Bp0;
    const float4 b1 = *(const float4*)Bp1;
    STAGE_WR(As[0], Bs[0], a0, a1, b0, b1);
  }
  __syncthreads();

  const int nt = K >> 4;
  for (int t = 0; t < nt; ++t) {
    float4 gA0, gA1, gB0, gB1;
    const bool more = (t + 1) < nt;
    if (more) {
      const int kc = (t + 1) << 4;
      gA0 = *(const float4*)(Ap0 + kc);
      gA1 = *(const float4*)(Ap1 + kc);
      gB0 = *(const float4*)(Bp0 + kc);
      gB1 = *(const float4*)(Bp1 + kc);
    }
    const float* __restrict__ Ab = As[t & 1];
    const float* __restrict__ Bb = Bs[t & 1];
#pragma unroll
    for (int k = 0; k < 16; ++k) {
      const float4 a0 = *(const float4*)&Ab[k * SST + ma0];
      const float4 a1 = *(const float4*)&Ab[k * SST + ma0 + 32];
      const float4 b0 = *(const float4*)&Bb[k * SST + nb0];
      const float4 b1 = *(const float4*)&Bb[k * SST + nb0 + 32];
      FMA_ROW(a0.x, c00, c01)
      FMA_ROW(a0.y, c10, c11)
      FMA_ROW(a0.z, c20, c21)
      FMA_ROW(a0.w, c30, c31)
      FMA_ROW(a1.x, c40, c41)
      FMA_ROW(a1.y, c50, c51)
      FMA_ROW(a1.z, c60, c61)
      FMA_ROW(a1.w, c70, c71)
    }
    if (more) STAGE_WR(As[(t & 1) ^ 1], Bs[(t & 1) ^ 1], gA0, gA1, gB0, gB1);
    __syncthreads();
  }
#undef STAGE_WR
#undef FMA_ROW

  // epilogue: bias + activation + remapped store
  const float4 bv0 = *(const float4*)&bias[n0 + nb0];
  const float4 bv1 = *(const float4*)&bias[n0 + nb0 + 32];
#define EPI_ROW(IDX, C0, C1)                                         \
  {                                                                  \
    const int m = mA + ma0 + ((IDX) < 4 ? (IDX) : 28 + (IDX));       \
    int cr;                                                          \
    if (RMAP == 0) cr = m;                                           \
    else if (RMAP == 1) cr = (m % 80) * 128 + m / 80;                \
    else cr = (m & 127) * 10 + (m >> 7);                             \
    float* Cp = C + (size_t)cr * ldc + n0 + nb0;                     \
    float4 o0, o1;                                                   \
    float v;                                                         \
    v = C0.x + bv0.x; o0.x = ACT ? fmaxf(v, 0.f) : v;                \
    v = C0.y + bv0.y; o0.y = ACT ? fmaxf(v, 0.f) : v;                \
    v = C0.z + bv0.z; o0.z = ACT ? fmaxf(v, 0.f) : v;                \
    v = C0.w + bv0.w; o0.w = ACT ? fmaxf(v, 0.f) : v;                \
    v = C1.x + bv1.x; o1.x = ACT ? fmaxf(v, 0.f) : v;                \
    v = C1.y + bv1.y; o1.y = ACT ? fmaxf(v, 0.f) : v;                \
    v = C1.z + bv1.z; o1.z = ACT ? fmaxf(v, 0.f) : v;                \
    v = C1.w + bv1.w; o1.w = ACT ? fmaxf(v, 0.f) : v;                \
    *(float4*)&Cp[0] = o0;                                           \
    *(float4*)&Cp[32] = o1;                                          \
  }
  EPI_ROW(0, c00, c01)
  EPI_ROW(1, c10, c11)
  EPI_ROW(2, c20, c21)
  EPI_ROW(3, c30, c31)
  EPI_ROW(4, c40, c41)
  EPI_ROW(5, c50, c51)
  EPI_ROW(6, c60, c61)
  EPI_ROW(7, c70, c71)
#undef EPI_ROW
}

// =====================================================================
// One GRU recurrence step. Grid: (jt=64, bt=4, d=dirs). Block 256.
// gh = h_prev @ whh^T (+bhh), gates fused, writes h_next and y.
// gi rows are (t*128+b), columns [d*1536 + gate*512 + j].
// h buffers: (dirs,128,512). y row (t*128+b), y_ld cols, offset d*512.
// =====================================================================
__global__ __launch_bounds__(256, 2) void gru_step_k(
    const float* __restrict__ h_prev, float* __restrict__ h_next,
    const float* __restrict__ gi, int gi_ld, const float* __restrict__ whh,
    const float* __restrict__ bhh, float* __restrict__ y, int y_ld, int i,
    int T) {
  __shared__ float lds_h[32 * 516];
  __shared__ float gh_lds[24 * 33];
  const int tid = threadIdx.x;
  const int jt = blockIdx.x; // 0..63  (8 h-outputs each)
  const int bt = blockIdx.y; // 0..3   (32 batch rows each)
  const int d = blockIdx.z;
  const int t_d = (d == 0) ? i : (T - 1 - i);
  const int doff = d * 1536;

  // stage h tile (32 x 512) into LDS, stride 516
  {
    const float* hp = h_prev + ((size_t)(d * 128 + bt * 32)) * 512;
#pragma unroll
    for (int c = 0; c < 16; ++c) {
      const int i4 = c * 256 + tid;
      const int r = i4 >> 7;
      const int k4 = i4 & 127;
      *(float4*)&lds_h[r * 516 + k4 * 4] =
          *(const float4*)&hp[(size_t)r * 512 + k4 * 4];
    }
  }
  __syncthreads();

  const int w = __builtin_amdgcn_readfirstlane(tid >> 6);
  const int lane = tid & 63;
  const int b_loc = lane & 31;
  const int kh = lane >> 5;

  const float* wr[6];
#pragma unroll
  for (int q = 0; q < 6; ++q) {
    const int rl = w * 6 + q;
    const int g = rl >> 3, jh = rl & 7;
    wr[q] = whh + ((size_t)(doff + g * 512 + jt * 8 + jh)) * 512;
  }
  float acc[6] = {0.f, 0.f, 0.f, 0.f, 0.f, 0.f};
  const int kbase = kh * 256;
  for (int k8 = 0; k8 < 256; k8 += 8) {
    const float4 a0 = *(const float4*)&lds_h[b_loc * 516 + kbase + k8];
    const float4 a1 = *(const float4*)&lds_h[b_loc * 516 + kbase + k8 + 4];
#pragma unroll
    for (int q = 0; q < 6; ++q) {
      const float* r_ = wr[q] + kbase + k8;
      acc[q] += r_[0] * a0.x + r_[1] * a0.y + r_[2] * a0.z + r_[3] * a0.w +
                r_[4] * a1.x + r_[5] * a1.y + r_[6] * a1.z + r_[7] * a1.w;
    }
  }
#pragma unroll
  for (int q = 0; q < 6; ++q) acc[q] += __shfl_xor(acc[q], 32);
  if (kh == 0) {
#pragma unroll
    for (int q = 0; q < 6; ++q) gh_lds[(w * 6 + q) * 33 + b_loc] = acc[q];
  }
  __syncthreads();

  // gate phase: thread -> (jh2, b2)
  const int jh2 = tid & 7;
  const int b2 = tid >> 3; // 0..31
  const int jg = jt * 8 + jh2;
  const int bg = bt * 32 + b2;
  const float ghr = gh_lds[(jh2) * 33 + b2];
  const float ghz = gh_lds[(8 + jh2) * 33 + b2];
  const float ghn = gh_lds[(16 + jh2) * 33 + b2];
  const float* gir = gi + (size_t)(t_d * 128 + bg) * gi_ld + doff;
  const float g_r = gir[jg];
  const float g_z = gir[512 + jg];
  const float g_n = gir[1024 + jg];
  const float r = sigmf(g_r + ghr + bhh[doff + jg]);
  const float z = sigmf(g_z + ghz + bhh[doff + 512 + jg]);
  const float n = tanhf(g_n + r * (ghn + bhh[doff + 1024 + jg]));
  const float hold = lds_h[b2 * 516 + jg];
  const float hnew = (1.f - z) * n + z * hold;
  h_next[((size_t)(d * 128 + bg)) * 512 + jg] = hnew;
  y[((size_t)(t_d * 128 + bg)) * y_ld + d * 512 + jg] = hnew;
}

// =====================================================================
// encode_out[t,b,h] = y1[t,b,h] + y1[t,b,512+h]   (float4 granularity)
// =====================================================================
__global__ void fold_k(const float* __restrict__ y1, float* __restrict__ eo) {
  const size_t i = (size_t)blockIdx.x * 256 + threadIdx.x; // float4 index
  const size_t r = i >> 7;
  const int k4 = (int)(i & 127);
  const float* s = y1 + r * 1024 + k4 * 4;
  const float4 a = *(const float4*)s;
  const float4 c = *(const float4*)(s + 512);
  float4 o;
  o.x = a.x + c.x; o.y = a.y + c.y; o.z = a.z + c.z; o.w = a.w + c.w;
  *(float4*)&eo[r * 512 + k4 * 4] = o;
}

// emb_g[l*128+b, :] = embed[target[b,l], :]
__global__ void gather_k(const float* __restrict__ embed,
                         const int* __restrict__ target,
                         float* __restrict__ out) {
  const int rowid = blockIdx.x; // l*128+b
  const int l = rowid >> 7, b = rowid & 127;
  const int wd = target[b * 10 + l];
  const float4* src = (const float4*)(embed + (size_t)wd * 512);
  float4* dst = (float4*)(out + (size_t)rowid * 512);
  dst[threadIdx.x] = src[threadIdx.x];
}

// =====================================================================
// Attention per (l,b): scores over T=80, softmax, ctx; writes Z row
// [ctx(512) | hn(512)].  enc: (T,B,512) rows t*128+b. hn: (L*B,512).
// =====================================================================
__global__ __launch_bounds__(256) void attn_k(const float* __restrict__ enc,
                                              const float* __restrict__ hn_all,
                                              float* __restrict__ Z) {
  __shared__ float hs[512];
  __shared__ float sc[80];
  __shared__ float att[80];
  const int l = blockIdx.x >> 7;
  const int b = blockIdx.x & 127;
  const int tid = threadIdx.x;
  const size_t hrow = (size_t)(l * 128 + b) * 512;
  if (tid < 128)
    *(float4*)&hs[tid * 4] = *(const float4*)&hn_all[hrow + tid * 4];
  __syncthreads();
  const int w = tid >> 6, lane = tid & 63;
  for (int t = w; t < 80; t += 4) {
    const float* e = enc + ((size_t)(t * 128 + b)) * 512 + lane * 8;
    const float4 e0 = *(const float4*)e;
    const float4 e1 = *(const float4*)(e + 4);
    const float* h8 = &hs[lane * 8];
    float p = e0.x * h8[0] + e0.y * h8[1] + e0.z * h8[2] + e0.w * h8[3] +
              e1.x * h8[4] + e1.y * h8[5] + e1.z * h8[6] + e1.w * h8[7];
#pragma unroll
    for (int off = 1; off < 64; off <<= 1) p += __shfl_xor(p, off);
    if (lane == 0) sc[t] = p;
  }
  __syncthreads();
  if (w == 0) {
    const float v0 = sc[lane];
    const float v1 = (lane < 16) ? sc[64 + lane] : -3.4e38f;
    float m = fmaxf(v0, v1);
#pragma unroll
    for (int off = 1; off < 64; off <<= 1) m = fmaxf(m, __shfl_xor(m, off));
    const float e0 = expf(v0 - m);
    const float e1 = (lane < 16) ? expf(v1 - m) : 0.f;
    float s = e0 + e1;
#pragma unroll
    for (int off = 1; off < 64; off <<= 1) s += __shfl_xor(s, off);
    att[lane] = e0 / s;
    if (lane < 16) att[64 + lane] = e1 / s;
  }
  __syncthreads();
  float c0 = 0.f, c1 = 0.f;
  for (int t = 0; t < 80; ++t) {
    const float* e = enc + ((size_t)(t * 128 + b)) * 512;
    const float a = att[t];
    c0 += a * e[tid];
    c1 += a * e[tid + 256];
  }
  const size_t zr = (size_t)(l * 128 + b) * 1024;
  Z[zr + tid] = c0;
  Z[zr + 256 + tid] = c1;
  Z[zr + 512 + tid] = hs[tid];
  Z[zr + 768 + tid] = hs[256 + tid];
}

// =====================================================================
// Per row (b*10+l) of d_out: argmax (first-index ties) + logsumexp,
// in-place log_softmax, write pre_sent[l*128+b] as float.
// =====================================================================
__global__ __launch_bounds__(256) void lsm_k(float* __restrict__ out) {
  const int row = blockIdx.x; // b*10 + l
  float* p = out + (size_t)row * 32000;
  const int tid = threadIdx.x;
  float bv = -3.4e38f;
  int bi = 0;
  for (int c = 0; c < 125; ++c) {
    const int idx = c * 256 + tid;
    const float v = p[idx];
    if (v > bv || (v == bv && idx < bi)) { bv = v; bi = idx; }
  }
#pragma unroll
  for (int off = 1; off < 64; off <<= 1) {
    const float ov = __shfl_xor(bv, off);
    const int oi = __shfl_xor(bi, off);
    if (ov > bv || (ov == bv && oi < bi)) { bv = ov; bi = oi; }
  }
  __shared__ float wv[4];
  __shared__ int wi[4];
  __shared__ float wsm[4];
  const int w = tid >> 6, lane = tid & 63;
  if (lane == 0) { wv[w] = bv; wi[w] = bi; }
  __syncthreads();
  float m = wv[0];
  int mi = wi[0];
#pragma unroll
  for (int q = 1; q < 4; ++q) {
    if (wv[q] > m || (wv[q] == m && wi[q] < mi)) { m = wv[q]; mi = wi[q]; }
  }
  float s = 0.f;
  for (int c = 0; c < 125; ++c) s += expf(p[c * 256 + tid] - m);
#pragma unroll
  for (int off = 1; off < 64; off <<= 1) s += __shfl_xor(s, off);
  if (lane == 0) wsm[w] = s;
  __syncthreads();
  const float lse = m + logf(wsm[0] + wsm[1] + wsm[2] + wsm[3]);
  for (int c = 0; c < 125; ++c) {
    const int idx = c * 256 + tid;
    p[idx] = p[idx] - lse;
  }
  if (tid == 0) out[40960000 + (row % 10) * 128 + (row / 10)] = (float)mi;
}

// =====================================================================
extern "C" void kernel_launch(void* const* d_in, const int* in_sizes, int n_in,
                              void* d_out, int out_size, void* d_ws,
                              size_t ws_size, hipStream_t stream) {
  (void)in_sizes; (void)n_in; (void)out_size; (void)ws_size;
  const float* data = (const float*)d_in[0];
  const int* target = (const int*)d_in[1];
  const float* enc_lin_w = (const float*)d_in[2];
  const float* enc_lin_b = (const float*)d_in[3];
  const float* enc_wih0 = (const float*)d_in[4];
  const float* enc_whh0 = (const float*)d_in[5];
  const float* enc_bih0 = (const float*)d_in[6];
  const float* enc_bhh0 = (const float*)d_in[7];
  const float* enc_wih1 = (const float*)d_in[8];
  const float* enc_whh1 = (const float*)d_in[9];
  const float* enc_bih1 = (const float*)d_in[10];
  const float* enc_bhh1 = (const float*)d_in[11];
  const float* dec_wih = (const float*)d_in[12];
  const float* dec_whh = (const float*)d_in[13];
  const float* dec_bih = (const float*)d_in[14];
  const float* dec_bhh = (const float*)d_in[15];
  const float* out_w = (const float*)d_in[16];
  const float* out_b = (const float*)d_in[17];
  const float* embed = (const float*)d_in[18];
  float* outp = (float*)d_out;

  float* ws = (float*)d_ws;
  size_t off = 0;
  float* buf_gi = ws + off;  off += 31457280;  // (10240, 3072) gi0 then gi1
  float* buf_x = ws + off;   off += 5242880;   // x (T,B,512); later enc_out
  float* buf_y0 = ws + off;  off += 10485760;  // (T,B,1024)
  float* buf_y1 = ws + off;  off += 10485760;  // (T,B,1024)
  float* h_pp0 = ws + off;   off += 131072;    // (2,128,512)
  float* h_pp1 = ws + off;   off += 131072;
  float* dec_pp0 = ws + off; off += 65536;     // (128,512)
  float* dec_pp1 = ws + off; off += 65536;
  float* emb_g = ws + off;   off += 655360;    // (1280,512)
  float* gi_dec = ws + off;  off += 1966080;   // (1280,1536)
  float* hn_all = ws + off;  off += 655360;    // (1280,512)
  float* Zb = ws + off;      off += 1310720;   // (1280,1024)

  // ---- Encoder linear + ReLU: x(t*128+b, 512) ----
  gemm_k<1, 1><<<dim3(4, 80), 256, 0, stream>>>(data, enc_lin_w, enc_lin_b,
                                                buf_x, 4096, 512);
  // ---- gi0 = x @ wih0^T (+bih0), both dirs stacked in 3072 cols ----
  gemm_k<0, 0><<<dim3(24, 80), 256, 0, stream>>>(buf_x, enc_wih0, enc_bih0,
                                                 buf_gi, 512, 3072);
  // ---- layer-0 recurrence ----
  hipMemsetAsync(h_pp0, 0, 2 * 128 * 512 * sizeof(float), stream);
  for (int i = 0; i < 80; ++i) {
    float* hin = (i & 1) ? h_pp1 : h_pp0;
    float* hout = (i & 1) ? h_pp0 : h_pp1;
    gru_step_k<<<dim3(64, 4, 2), 256, 0, stream>>>(
        hin, hout, buf_gi, 3072, enc_whh0, enc_bhh0, buf_y0, 1024, i, 80);
  }
  // ---- gi1 = y0 @ wih1^T (+bih1) ----
  gemm_k<0, 0><<<dim3(24, 80), 256, 0, stream>>>(buf_y0, enc_wih1, enc_bih1,
                                                 buf_gi, 1024, 3072);
  // ---- layer-1 recurrence ----
  hipMemsetAsync(h_pp0, 0, 2 * 128 * 512 * sizeof(float), stream);
  for (int i = 0; i < 80; ++i) {
    float* hin = (i & 1) ? h_pp1 : h_pp0;
    float* hout = (i & 1) ? h_pp0 : h_pp1;
    gru_step_k<<<dim3(64, 4, 2), 256, 0, stream>>>(
        hin, hout, buf_gi, 3072, enc_whh1, enc_bhh1, buf_y1, 1024, i, 80);
  }
  // final hidden (both dirs) now in h_pp0; decode_hid = d=1 slice.
  // ---- encode_out = y1[:, :512] + y1[:, 512:]  (into buf_x) ----
  fold_k<<<5120, 256, 0, stream>>>(buf_y1, buf_x);
  // ---- decoder input projections ----
  gather_k<<<1280, 128, 0, stream>>>(embed, target, emb_g);
  gemm_k<0, 0><<<dim3(12, 10), 256, 0, stream>>>(emb_g, dec_wih, dec_bih,
                                                 gi_dec, 512, 1536);
  // ---- decoder hidden chain (teacher forcing => independent of logits) ----
  for (int l = 0; l < 10; ++l) {
    float* hin = (l == 0) ? (h_pp0 + 128 * 512) : ((l & 1) ? dec_pp1 : dec_pp0);
    float* hout = (l & 1) ? dec_pp0 : dec_pp1;
    gru_step_k<<<dim3(64, 4, 1), 256, 0, stream>>>(
        hin, hout, gi_dec, 1536, dec_whh, dec_bhh, hn_all, 512, l, 10);
  }
  // ---- attention + Z = [ctx | hn] ----
  attn_k<<<1280, 256, 0, stream>>>(buf_x, hn_all, Zb);
  // ---- logits GEMM straight into d_out rows (b*10+l) ----
  gemm_k<0, 2><<<dim3(250, 10), 256, 0, stream>>>(Zb, out_w, out_b, outp, 1024,
                                                  32000);
  // ---- log_softmax in place + argmax -> pre_sent ----
  lsm_k<<<1280, 256, 0, stream>>>(outp);
}

// Round 4
// 7677.384 us; speedup vs baseline: 6.4565x; 2.8332x over previous
//
#include <hip/hip_runtime.h>
#include <cstdint>
#include <cstddef>

#define DEVFN __device__ __forceinline__

DEVFN float sigmf(float x) { return 1.0f / (1.0f + expf(-x)); }

// =====================================================================
// GEMM v4: C[rowmap(m), n] = act( sum_k A[m,k]*B[n,k] + bias[n] )
// A: (M,K) row-major. B: (N,K) row-major (C = A @ B^T).
// Block 512 thr = 8 waves (4m x 2n), macro-tile 128x128, BK=16.
// Per-lane tile 4m x 8n = 8 named float4 accumulators (~72 VGPR base
// demand -> fits the 128-VGPR cap of __launch_bounds__(512,4) with
// slack; R2/R3's 8x8-per-lane at 256thr spilled to scratch: 19 GB/disp).
// Operands staged TRANSPOSED in LDS [k][m]/[k][n], stride 132
// (staging ds_writes 2-way conflict = free; frag reads broadcast).
// Double-buffered LDS, 1 barrier per K-step.
// RMAP: 0 identity; 1: (m%80)*128+m/80 ; 2: (m&127)*10+(m>>7)
// Requires: M%128==0, N%128==0, K%16==0.
// =====================================================================
template <int ACT, int RMAP>
__global__ __launch_bounds__(512, 4) void gemm_k(
    const float* __restrict__ A, const float* __restrict__ B,
    const float* __restrict__ bias, float* __restrict__ C, int K, int ldc) {
  constexpr int SST = 132;
  __shared__ float As[2][16 * SST];
  __shared__ float Bs[2][16 * SST];
  const int tid = threadIdx.x;
  const int mA = blockIdx.y * 128;
  const int n0 = blockIdx.x * 128;

  // staging: each thread owns one float4 of A and one of B per k-tile
  const int sm = tid >> 2;  // 0..127 (tile row)
  const int sq = tid & 3;   // k-quad 0..3
  const float* __restrict__ Ap = A + (size_t)(mA + sm) * K + sq * 4;
  const float* __restrict__ Bp = B + (size_t)(n0 + sm) * K + sq * 4;

  const int w = tid >> 6;   // 0..7
  const int lane = tid & 63;
  const int am0 = (w >> 1) * 32 + (lane >> 3) * 4;  // LDS m base (4 rows)
  const int bn0 = (w & 1) * 64 + (lane & 7) * 4;    // LDS n base (8 cols)

  const float4 fz = {0.f, 0.f, 0.f, 0.f};
  float4 c0a = fz, c0b = fz, c1a = fz, c1b = fz, c2a = fz, c2b = fz,
         c3a = fz, c3b = fz;

#define STAGE_WR(AW, BW, ga, gb)          \
  do {                                    \
    const int kq = sq * 4;                \
    (AW)[(kq + 0) * SST + sm] = (ga).x;   \
    (AW)[(kq + 1) * SST + sm] = (ga).y;   \
    (AW)[(kq + 2) * SST + sm] = (ga).z;   \
    (AW)[(kq + 3) * SST + sm] = (ga).w;   \
    (BW)[(kq + 0) * SST + sm] = (gb).x;   \
    (BW)[(kq + 1) * SST + sm] = (gb).y;   \
    (BW)[(kq + 2) * SST + sm] = (gb).z;   \
    (BW)[(kq + 3) * SST + sm] = (gb).w;   \
  } while (0)

#define FMA8(AV, CA, CB)            \
  CA.x = fmaf(AV, b0.x, CA.x);      \
  CA.y = fmaf(AV, b0.y, CA.y);      \
  CA.z = fmaf(AV, b0.z, CA.z);      \
  CA.w = fmaf(AV, b0.w, CA.w);      \
  CB.x = fmaf(AV, b1.x, CB.x);      \
  CB.y = fmaf(AV, b1.y, CB.y);      \
  CB.z = fmaf(AV, b1.z, CB.z);      \
  CB.w = fmaf(AV, b1.w, CB.w);

#define COMPUTE_TILE(Ab, Bb)                                    \
  _Pragma("unroll") for (int k = 0; k < 16; ++k) {              \
    const float4 av = *(const float4*)&(Ab)[k * SST + am0];     \
    const float4 b0 = *(const float4*)&(Bb)[k * SST + bn0];     \
    const float4 b1 = *(const float4*)&(Bb)[k * SST + bn0 + 32];\
    FMA8(av.x, c0a, c0b)                                        \
    FMA8(av.y, c1a, c1b)                                        \
    FMA8(av.z, c2a, c2b)                                        \
    FMA8(av.w, c3a, c3b)                                        \
  }

  // prologue: stage tile 0 into buffer 0
  {
    const float4 ga = *(const float4*)Ap;
    const float4 gb = *(const float4*)Bp;
    STAGE_WR(As[0], Bs[0], ga, gb);
  }
  __syncthreads();

  const int nt = K >> 4;
  for (int t = 0; t < nt - 1; ++t) {
    const int kc = (t + 1) << 4;
    const float4 ga = *(const float4*)(Ap + kc);
    const float4 gb = *(const float4*)(Bp + kc);
    const float* __restrict__ Ab = As[t & 1];
    const float* __restrict__ Bb = Bs[t & 1];
    COMPUTE_TILE(Ab, Bb)
    STAGE_WR(As[(t & 1) ^ 1], Bs[(t & 1) ^ 1], ga, gb);
    __syncthreads();
  }
  {
    const float* __restrict__ Ab = As[(nt - 1) & 1];
    const float* __restrict__ Bb = Bs[(nt - 1) & 1];
    COMPUTE_TILE(Ab, Bb)
  }
#undef STAGE_WR
#undef FMA8
#undef COMPUTE_TILE

  // epilogue: bias + activation + remapped store
  const float4 bv0 = *(const float4*)&bias[n0 + bn0];
  const float4 bv1 = *(const float4*)&bias[n0 + bn0 + 32];
#define EPI_ROW(IDX, CA, CB)                                         \
  {                                                                  \
    const int m = mA + am0 + (IDX);                                  \
    int cr;                                                          \
    if (RMAP == 0) cr = m;                                           \
    else if (RMAP == 1) cr = (m % 80) * 128 + m / 80;                \
    else cr = (m & 127) * 10 + (m >> 7);                             \
    float* Cp = C + (size_t)cr * ldc + n0 + bn0;                     \
    float4 o0, o1;                                                   \
    float v;                                                         \
    v = CA.x + bv0.x; o0.x = ACT ? fmaxf(v, 0.f) : v;                \
    v = CA.y + bv0.y; o0.y = ACT ? fmaxf(v, 0.f) : v;                \
    v = CA.z + bv0.z; o0.z = ACT ? fmaxf(v, 0.f) : v;                \
    v = CA.w + bv0.w; o0.w = ACT ? fmaxf(v, 0.f) : v;                \
    v = CB.x + bv1.x; o1.x = ACT ? fmaxf(v, 0.f) : v;                \
    v = CB.y + bv1.y; o1.y = ACT ? fmaxf(v, 0.f) : v;                \
    v = CB.z + bv1.z; o1.z = ACT ? fmaxf(v, 0.f) : v;                \
    v = CB.w + bv1.w; o1.w = ACT ? fmaxf(v, 0.f) : v;                \
    *(float4*)&Cp[0] = o0;                                           \
    *(float4*)&Cp[32] = o1;                                          \
  }
  EPI_ROW(0, c0a, c0b)
  EPI_ROW(1, c1a, c1b)
  EPI_ROW(2, c2a, c2b)
  EPI_ROW(3, c3a, c3b)
#undef EPI_ROW
}

// =====================================================================
// One GRU recurrence step. Grid: (jt=64, bt=4, d=dirs). Block 256.
// gh = h_prev @ whh^T (+bhh), gates fused, writes h_next and y.
// gi rows are (t*128+b), columns [d*1536 + gate*512 + j].
// h buffers: (dirs,128,512). y row (t*128+b), y_ld cols, offset d*512.
// =====================================================================
__global__ __launch_bounds__(256, 2) void gru_step_k(
    const float* __restrict__ h_prev, float* __restrict__ h_next,
    const float* __restrict__ gi, int gi_ld, const float* __restrict__ whh,
    const float* __restrict__ bhh, float* __restrict__ y, int y_ld, int i,
    int T) {
  __shared__ float lds_h[32 * 516];
  __shared__ float gh_lds[24 * 33];
  const int tid = threadIdx.x;
  const int jt = blockIdx.x; // 0..63  (8 h-outputs each)
  const int bt = blockIdx.y; // 0..3   (32 batch rows each)
  const int d = blockIdx.z;
  const int t_d = (d == 0) ? i : (T - 1 - i);
  const int doff = d * 1536;

  // stage h tile (32 x 512) into LDS, stride 516
  {
    const float* hp = h_prev + ((size_t)(d * 128 + bt * 32)) * 512;
#pragma unroll
    for (int c = 0; c < 16; ++c) {
      const int i4 = c * 256 + tid;
      const int r = i4 >> 7;
      const int k4 = i4 & 127;
      *(float4*)&lds_h[r * 516 + k4 * 4] =
          *(const float4*)&hp[(size_t)r * 512 + k4 * 4];
    }
  }
  __syncthreads();

  const int w = __builtin_amdgcn_readfirstlane(tid >> 6);
  const int lane = tid & 63;
  const int b_loc = lane & 31;
  const int kh = lane >> 5;

  const float* wr[6];
#pragma unroll
  for (int q = 0; q < 6; ++q) {
    const int rl = w * 6 + q;
    const int g = rl >> 3, jh = rl & 7;
    wr[q] = whh + ((size_t)(doff + g * 512 + jt * 8 + jh)) * 512;
  }
  float acc[6] = {0.f, 0.f, 0.f, 0.f, 0.f, 0.f};
  const int kbase = kh * 256;
  for (int k8 = 0; k8 < 256; k8 += 8) {
    const float4 a0 = *(const float4*)&lds_h[b_loc * 516 + kbase + k8];
    const float4 a1 = *(const float4*)&lds_h[b_loc * 516 + kbase + k8 + 4];
#pragma unroll
    for (int q = 0; q < 6; ++q) {
      const float* r_ = wr[q] + kbase + k8;
      acc[q] += r_[0] * a0.x + r_[1] * a0.y + r_[2] * a0.z + r_[3] * a0.w +
                r_[4] * a1.x + r_[5] * a1.y + r_[6] * a1.z + r_[7] * a1.w;
    }
  }
#pragma unroll
  for (int q = 0; q < 6; ++q) acc[q] += __shfl_xor(acc[q], 32);
  if (kh == 0) {
#pragma unroll
    for (int q = 0; q < 6; ++q) gh_lds[(w * 6 + q) * 33 + b_loc] = acc[q];
  }
  __syncthreads();

  // gate phase: thread -> (jh2, b2)
  const int jh2 = tid & 7;
  const int b2 = tid >> 3; // 0..31
  const int jg = jt * 8 + jh2;
  const int bg = bt * 32 + b2;
  const float ghr = gh_lds[(jh2) * 33 + b2];
  const float ghz = gh_lds[(8 + jh2) * 33 + b2];
  const float ghn = gh_lds[(16 + jh2) * 33 + b2];
  const float* gir = gi + (size_t)(t_d * 128 + bg) * gi_ld + doff;
  const float g_r = gir[jg];
  const float g_z = gir[512 + jg];
  const float g_n = gir[1024 + jg];
  const float r = sigmf(g_r + ghr + bhh[doff + jg]);
  const float z = sigmf(g_z + ghz + bhh[doff + 512 + jg]);
  const float n = tanhf(g_n + r * (ghn + bhh[doff + 1024 + jg]));
  const float hold = lds_h[b2 * 516 + jg];
  const float hnew = (1.f - z) * n + z * hold;
  h_next[((size_t)(d * 128 + bg)) * 512 + jg] = hnew;
  y[((size_t)(t_d * 128 + bg)) * y_ld + d * 512 + jg] = hnew;
}

// =====================================================================
// encode_out[t,b,h] = y1[t,b,h] + y1[t,b,512+h]   (float4 granularity)
// =====================================================================
__global__ void fold_k(const float* __restrict__ y1, float* __restrict__ eo) {
  const size_t i = (size_t)blockIdx.x * 256 + threadIdx.x; // float4 index
  const size_t r = i >> 7;
  const int k4 = (int)(i & 127);
  const float* s = y1 + r * 1024 + k4 * 4;
  const float4 a = *(const float4*)s;
  const float4 c = *(const float4*)(s + 512);
  float4 o;
  o.x = a.x + c.x; o.y = a.y + c.y; o.z = a.z + c.z; o.w = a.w + c.w;
  *(float4*)&eo[r * 512 + k4 * 4] = o;
}

// emb_g[l*128+b, :] = embed[target[b,l], :]
__global__ void gather_k(const float* __restrict__ embed,
                         const int* __restrict__ target,
                         float* __restrict__ out) {
  const int rowid = blockIdx.x; // l*128+b
  const int l = rowid >> 7, b = rowid & 127;
  const int wd = target[b * 10 + l];
  const float4* src = (const float4*)(embed + (size_t)wd * 512);
  float4* dst = (float4*)(out + (size_t)rowid * 512);
  dst[threadIdx.x] = src[threadIdx.x];
}

// =====================================================================
// Attention per (l,b): scores over T=80, softmax, ctx; writes Z row
// [ctx(512) | hn(512)].  enc: (T,B,512) rows t*128+b. hn: (L*B,512).
// =====================================================================
__global__ __launch_bounds__(256) void attn_k(const float* __restrict__ enc,
                                              const float* __restrict__ hn_all,
                                              float* __restrict__ Z) {
  __shared__ float hs[512];
  __shared__ float sc[80];
  __shared__ float att[80];
  const int l = blockIdx.x >> 7;
  const int b = blockIdx.x & 127;
  const int tid = threadIdx.x;
  const size_t hrow = (size_t)(l * 128 + b) * 512;
  if (tid < 128)
    *(float4*)&hs[tid * 4] = *(const float4*)&hn_all[hrow + tid * 4];
  __syncthreads();
  const int w = tid >> 6, lane = tid & 63;
  for (int t = w; t < 80; t += 4) {
    const float* e = enc + ((size_t)(t * 128 + b)) * 512 + lane * 8;
    const float4 e0 = *(const float4*)e;
    const float4 e1 = *(const float4*)(e + 4);
    const float* h8 = &hs[lane * 8];
    float p = e0.x * h8[0] + e0.y * h8[1] + e0.z * h8[2] + e0.w * h8[3] +
              e1.x * h8[4] + e1.y * h8[5] + e1.z * h8[6] + e1.w * h8[7];
#pragma unroll
    for (int off = 1; off < 64; off <<= 1) p += __shfl_xor(p, off);
    if (lane == 0) sc[t] = p;
  }
  __syncthreads();
  if (w == 0) {
    const float v0 = sc[lane];
    const float v1 = (lane < 16) ? sc[64 + lane] : -3.4e38f;
    float m = fmaxf(v0, v1);
#pragma unroll
    for (int off = 1; off < 64; off <<= 1) m = fmaxf(m, __shfl_xor(m, off));
    const float e0 = expf(v0 - m);
    const float e1 = (lane < 16) ? expf(v1 - m) : 0.f;
    float s = e0 + e1;
#pragma unroll
    for (int off = 1; off < 64; off <<= 1) s += __shfl_xor(s, off);
    att[lane] = e0 / s;
    if (lane < 16) att[64 + lane] = e1 / s;
  }
  __syncthreads();
  float c0 = 0.f, c1 = 0.f;
  for (int t = 0; t < 80; ++t) {
    const float* e = enc + ((size_t)(t * 128 + b)) * 512;
    const float a = att[t];
    c0 += a * e[tid];
    c1 += a * e[tid + 256];
  }
  const size_t zr = (size_t)(l * 128 + b) * 1024;
  Z[zr + tid] = c0;
  Z[zr + 256 + tid] = c1;
  Z[zr + 512 + tid] = hs[tid];
  Z[zr + 768 + tid] = hs[256 + tid];
}

// =====================================================================
// Per row (b*10+l) of d_out: argmax (first-index ties) + logsumexp,
// in-place log_softmax, write pre_sent[l*128+b] as float.
// =====================================================================
__global__ __launch_bounds__(256) void lsm_k(float* __restrict__ out) {
  const int row = blockIdx.x; // b*10 + l
  float* p = out + (size_t)row * 32000;
  const int tid = threadIdx.x;
  float bv = -3.4e38f;
  int bi = 0;
  for (int c = 0; c < 125; ++c) {
    const int idx = c * 256 + tid;
    const float v = p[idx];
    if (v > bv || (v == bv && idx < bi)) { bv = v; bi = idx; }
  }
#pragma unroll
  for (int off = 1; off < 64; off <<= 1) {
    const float ov = __shfl_xor(bv, off);
    const int oi = __shfl_xor(bi, off);
    if (ov > bv || (ov == bv && oi < bi)) { bv = ov; bi = oi; }
  }
  __shared__ float wv[4];
  __shared__ int wi[4];
  __shared__ float wsm[4];
  const int w = tid >> 6, lane = tid & 63;
  if (lane == 0) { wv[w] = bv; wi[w] = bi; }
  __syncthreads();
  float m = wv[0];
  int mi = wi[0];
#pragma unroll
  for (int q = 1; q < 4; ++q) {
    if (wv[q] > m || (wv[q] == m && wi[q] < mi)) { m = wv[q]; mi = wi[q]; }
  }
  float s = 0.f;
  for (int c = 0; c < 125; ++c) s += expf(p[c * 256 + tid] - m);
#pragma unroll
  for (int off = 1; off < 64; off <<= 1) s += __shfl_xor(s, off);
  if (lane == 0) wsm[w] = s;
  __syncthreads();
  const float lse = m + logf(wsm[0] + wsm[1] + wsm[2] + wsm[3]);
  for (int c = 0; c < 125; ++c) {
    const int idx = c * 256 + tid;
    p[idx] = p[idx] - lse;
  }
  if (tid == 0) out[40960000 + (row % 10) * 128 + (row / 10)] = (float)mi;
}

// =====================================================================
extern "C" void kernel_launch(void* const* d_in, const int* in_sizes, int n_in,
                              void* d_out, int out_size, void* d_ws,
                              size_t ws_size, hipStream_t stream) {
  (void)in_sizes; (void)n_in; (void)out_size; (void)ws_size;
  const float* data = (const float*)d_in[0];
  const int* target = (const int*)d_in[1];
  const float* enc_lin_w = (const float*)d_in[2];
  const float* enc_lin_b = (const float*)d_in[3];
  const float* enc_wih0 = (const float*)d_in[4];
  const float* enc_whh0 = (const float*)d_in[5];
  const float* enc_bih0 = (const float*)d_in[6];
  const float* enc_bhh0 = (const float*)d_in[7];
  const float* enc_wih1 = (const float*)d_in[8];
  const float* enc_whh1 = (const float*)d_in[9];
  const float* enc_bih1 = (const float*)d_in[10];
  const float* enc_bhh1 = (const float*)d_in[11];
  const float* dec_wih = (const float*)d_in[12];
  const float* dec_whh = (const float*)d_in[13];
  const float* dec_bih = (const float*)d_in[14];
  const float* dec_bhh = (const float*)d_in[15];
  const float* out_w = (const float*)d_in[16];
  const float* out_b = (const float*)d_in[17];
  const float* embed = (const float*)d_in[18];
  float* outp = (float*)d_out;

  float* ws = (float*)d_ws;
  size_t off = 0;
  float* buf_gi = ws + off;  off += 31457280;  // (10240, 3072) gi0 then gi1
  float* buf_x = ws + off;   off += 5242880;   // x (T,B,512); later enc_out
  float* buf_y0 = ws + off;  off += 10485760;  // (T,B,1024)
  float* buf_y1 = ws + off;  off += 10485760;  // (T,B,1024)
  float* h_pp0 = ws + off;   off += 131072;    // (2,128,512)
  float* h_pp1 = ws + off;   off += 131072;
  float* dec_pp0 = ws + off; off += 65536;     // (128,512)
  float* dec_pp1 = ws + off; off += 65536;
  float* emb_g = ws + off;   off += 655360;    // (1280,512)
  float* gi_dec = ws + off;  off += 1966080;   // (1280,1536)
  float* hn_all = ws + off;  off += 655360;    // (1280,512)
  float* Zb = ws + off;      off += 1310720;   // (1280,1024)

  // ---- Encoder linear + ReLU: x(t*128+b, 512) ----
  gemm_k<1, 1><<<dim3(4, 80), 512, 0, stream>>>(data, enc_lin_w, enc_lin_b,
                                                buf_x, 4096, 512);
  // ---- gi0 = x @ wih0^T (+bih0), both dirs stacked in 3072 cols ----
  gemm_k<0, 0><<<dim3(24, 80), 512, 0, stream>>>(buf_x, enc_wih0, enc_bih0,
                                                 buf_gi, 512, 3072);
  // ---- layer-0 recurrence ----
  hipMemsetAsync(h_pp0, 0, 2 * 128 * 512 * sizeof(float), stream);
  for (int i = 0; i < 80; ++i) {
    float* hin = (i & 1) ? h_pp1 : h_pp0;
    float* hout = (i & 1) ? h_pp0 : h_pp1;
    gru_step_k<<<dim3(64, 4, 2), 256, 0, stream>>>(
        hin, hout, buf_gi, 3072, enc_whh0, enc_bhh0, buf_y0, 1024, i, 80);
  }
  // ---- gi1 = y0 @ wih1^T (+bih1) ----
  gemm_k<0, 0><<<dim3(24, 80), 512, 0, stream>>>(buf_y0, enc_wih1, enc_bih1,
                                                 buf_gi, 1024, 3072);
  // ---- layer-1 recurrence ----
  hipMemsetAsync(h_pp0, 0, 2 * 128 * 512 * sizeof(float), stream);
  for (int i = 0; i < 80; ++i) {
    float* hin = (i & 1) ? h_pp1 : h_pp0;
    float* hout = (i & 1) ? h_pp0 : h_pp1;
    gru_step_k<<<dim3(64, 4, 2), 256, 0, stream>>>(
        hin, hout, buf_gi, 3072, enc_whh1, enc_bhh1, buf_y1, 1024, i, 80);
  }
  // final hidden (both dirs) now in h_pp0; decode_hid = d=1 slice.
  // ---- encode_out = y1[:, :512] + y1[:, 512:]  (into buf_x) ----
  fold_k<<<5120, 256, 0, stream>>>(buf_y1, buf_x);
  // ---- decoder input projections ----
  gather_k<<<1280, 128, 0, stream>>>(embed, target, emb_g);
  gemm_k<0, 0><<<dim3(12, 10), 512, 0, stream>>>(emb_g, dec_wih, dec_bih,
                                                 gi_dec, 512, 1536);
  // ---- decoder hidden chain (teacher forcing => independent of logits) ----
  for (int l = 0; l < 10; ++l) {
    float* hin = (l == 0) ? (h_pp0 + 128 * 512) : ((l & 1) ? dec_pp1 : dec_pp0);
    float* hout = (l & 1) ? dec_pp0 : dec_pp1;
    gru_step_k<<<dim3(64, 4, 1), 256, 0, stream>>>(
        hin, hout, gi_dec, 1536, dec_whh, dec_bhh, hn_all, 512, l, 10);
  }
  // ---- attention + Z = [ctx | hn] ----
  attn_k<<<1280, 256, 0, stream>>>(buf_x, hn_all, Zb);
  // ---- logits GEMM straight into d_out rows (b*10+l) ----
  gemm_k<0, 2><<<dim3(250, 10), 512, 0, stream>>>(Zb, out_w, out_b, outp, 1024,
                                                  32000);
  // ---- log_softmax in place + argmax -> pre_sent ----
  lsm_k<<<1280, 256, 0, stream>>>(outp);
}